// Round 6
// baseline (226.990 us; speedup 1.0000x reference)
//
#include <hip/hip_runtime.h>
#include <hip/hip_bf16.h>
#include <stdint.h>

// B=4, T=2048, H=16, DH=64, EMB=1024; M = B*T = 8192; N_qkv = 3072.

typedef __attribute__((ext_vector_type(8))) short short8;
typedef __attribute__((ext_vector_type(4))) float floatx4;

extern "C" __device__ float __ocml_native_exp2_f32(float);  // -> v_exp_f32 (2^x)

__device__ __forceinline__ ushort f2bf(float f) {
  uint32_t u = __float_as_uint(f);
  u += 0x7fff + ((u >> 16) & 1);   // RNE; inputs are NaN-free
  return (ushort)(u >> 16);
}

#if __has_builtin(__builtin_amdgcn_cvt_pk_bf16_f32)
typedef __attribute__((ext_vector_type(2))) __bf16 bf16x2;
__device__ __forceinline__ uint32_t pack_bf16(float a, float b) {
  union { bf16x2 v; uint32_t u; } cv;
  cv.v = __builtin_amdgcn_cvt_pk_bf16_f32(a, b);
  return cv.u;
}
#else
__device__ __forceinline__ uint32_t pack_bf16(float a, float b) {
  uint32_t ua = __float_as_uint(a) + 0x8000u;
  uint32_t ub = __float_as_uint(b) + 0x8000u;
  return __builtin_amdgcn_perm(ub, ua, 0x07060302u);
}
#endif

// async global->LDS, 16B per lane; LDS dest is wave-uniform base + lane*16
__device__ __forceinline__ void gload16(const ushort* g, ushort* l) {
  __builtin_amdgcn_global_load_lds(
      (const __attribute__((address_space(1))) void*)g,
      (__attribute__((address_space(3))) void*)l, 16, 0, 0);
}

// merged fp32->bf16 convert of x (2097152 float4), w_qkv (786432), wo (262144)
__global__ __launch_bounds__(256) void cvt3_kernel(const float* __restrict__ x,
                                                   const float* __restrict__ wq,
                                                   const float* __restrict__ wo,
                                                   ushort* __restrict__ xo,
                                                   ushort* __restrict__ wqo,
                                                   ushort* __restrict__ woo) {
  int i = blockIdx.x * 256 + threadIdx.x;
  const float* in; ushort* out; int idx;
  if (i < 2097152)      { in = x;  out = xo;  idx = i; }
  else if (i < 2883584) { in = wq; out = wqo; idx = i - 2097152; }
  else                  { in = wo; out = woo; idx = i - 2883584; }
  float4 v = ((const float4*)in)[idx];
  ushort4 o;
  o.x = f2bf(v.x); o.y = f2bf(v.y); o.z = f2bf(v.z); o.w = f2bf(v.w);
  ((ushort4*)out)[idx] = o;
}

// ---------------------------------------------------------------------------
// QKV GEMM, 256x256 tile: C = A @ B^T, A:[8192,1024] bf16, Bw:[3072,1024].
// 8 waves (512 thr) as 2M x 4N -> each wave owns a 128x64 output tile.
// Rationale: LDS-read bytes per MFMA FLOP is set by the per-wave tile;
// 128x64 gives 85 FLOP/elem vs 64 for the old 64x64 -> MFMA pipe (not the
// LDS pipe) becomes the long pole.  BK=32, ring of 3 slots (A 256x32 +
// B 256x32 = 16384 ushorts = 32 KiB/slot, 96 KiB total).
// Schedule (proven in rounds 3-5): RAW s_barrier (never __syncthreads in the
// K-loop) + counted vmcnt(4) (= next tile's 4 gloads stay in flight across
// every barrier) + stage(u+2) issued between frag reads and MFMA burst.
// Slot written by stage(u+2) was last ds_read at iter u-1 (reads issued
// before iter-u's barrier; gload's LDS write lands >=L2 latency later).
// LDS swizzle: LDS[r][c] holds global chunk c^((r>>1)&3) (staging
// pre-swizzles the GLOBAL chunk; frag reads use chunk quad^((lrow>>1)&3)).
// Single frag set (no reg double-buffer): acc is 128 AGPRs; ds_read->MFMA
// latency is hidden by the co-resident wave on each SIMD (2 waves/SIMD).
// Grid 32x12 = 384 blocks @ 1 block/CU (1.5 rounds - accepted tail).
// Epilogue: q/k in two 128-row half-passes, v^T in two 128-col half-passes.
// ---------------------------------------------------------------------------
__global__ __launch_bounds__(512) void gemm256(const ushort* __restrict__ A,
                                               const ushort* __restrict__ Bw,
                                               ushort* __restrict__ qb,
                                               ushort* __restrict__ kb,
                                               ushort* __restrict__ vt) {
  constexpr int SLOT = 16384;                 // ushorts per ring slot (A+B)
  __shared__ ushort ring[3 * SLOT];           // 96 KiB
  int tid = threadIdx.x;
  int lane = tid & 63, wave = tid >> 6;
  int lrow = lane & 15, quad = lane >> 4;
  int wm = wave >> 2, wn = wave & 3;          // 2M x 4N wave grid
  int wm128 = wm * 128, wn64 = wn * 64;
  int m0 = blockIdx.x * 256, n0 = blockIdx.y * 256;

  // staging: thread covers (row = tid>>2 of a 128-row call, chunk = tid&3);
  // global chunk pre-swizzled by ((row>>1)&3) = (tid>>3)&3
  int srow = tid >> 2;                                   // 0..127
  int schunk8 = ((tid & 3) ^ ((tid >> 3) & 3)) * 8;
  const ushort* Ag0 = A + (size_t)(m0 + srow) * 1024 + schunk8;
  const ushort* Ag1 = Ag0 + (size_t)128 * 1024;
  const ushort* Bg0 = Bw + (size_t)(n0 + srow) * 1024 + schunk8;
  const ushort* Bg1 = Bg0 + (size_t)128 * 1024;
  int fo2 = (quad ^ ((lrow >> 1) & 3)) * 8;              // frag-read chunk

  const floatx4 zero4 = {0.f, 0.f, 0.f, 0.f};
  floatx4 acc[8][4];
#pragma unroll
  for (int i = 0; i < 8; i++)
#pragma unroll
    for (int j = 0; j < 4; j++) acc[i][j] = zero4;

  auto stage = [&](int slot, int t) {
    ushort* Sa = &ring[slot * SLOT];
    size_t kk = (size_t)t * 32;
    gload16(Ag0 + kk, &Sa[wave * 512]);                  // A rows   0..127
    gload16(Ag1 + kk, &Sa[4096 + wave * 512]);           // A rows 128..255
    gload16(Bg0 + kk, &Sa[8192 + wave * 512]);           // B rows   0..127
    gload16(Bg1 + kk, &Sa[12288 + wave * 512]);          // B rows 128..255
  };

#define BARRIER(N_)                                                           \
  asm volatile("s_waitcnt vmcnt(" #N_ ")" ::: "memory");                      \
  __builtin_amdgcn_s_barrier();                                               \
  asm volatile("" ::: "memory");

#define COMPUTE(CUR_, DOSTAGE_, NXT_, T_)                                     \
  {                                                                           \
    ushort* As_ = &ring[(CUR_)*SLOT];                                         \
    ushort* Bs_ = As_ + 8192;                                                 \
    short8 a_[8], b_[4];                                                      \
    _Pragma("unroll")                                                         \
    for (int mi = 0; mi < 8; mi++)                                            \
      a_[mi] = *(const short8*)(&As_[(wm128 + mi * 16 + lrow) * 32 + fo2]);   \
    _Pragma("unroll")                                                         \
    for (int nj = 0; nj < 4; nj++)                                            \
      b_[nj] = *(const short8*)(&Bs_[(wn64 + nj * 16 + lrow) * 32 + fo2]);    \
    if (DOSTAGE_) stage((NXT_), (T_));                                        \
    __builtin_amdgcn_s_setprio(1);                                            \
    _Pragma("unroll")                                                         \
    for (int mi = 0; mi < 8; mi++)                                            \
      _Pragma("unroll")                                                       \
      for (int nj = 0; nj < 4; nj++)                                          \
        acc[mi][nj] = __builtin_amdgcn_mfma_f32_16x16x32_bf16(                \
            a_[mi], b_[nj], acc[mi][nj], 0, 0, 0);                            \
    __builtin_amdgcn_s_setprio(0);                                            \
  }

  stage(0, 0); stage(1, 1);
  int cur = 0, nxt = 2;
#pragma unroll 1
  for (int u = 0; u < 30; ++u) {      // tiles 0..29, stages 2..31
    BARRIER(4)                         // tile u landed; tile u+1 in flight
    COMPUTE(cur, true, nxt, u + 2)
    cur = (cur == 2) ? 0 : cur + 1;
    nxt = (nxt == 2) ? 0 : nxt + 1;
  }
  BARRIER(4)                           // tile 30 landed; tile 31 in flight
  COMPUTE(cur, false, 0, 0)
  cur = (cur == 2) ? 0 : cur + 1;
  BARRIER(0)                           // tile 31 landed
  COMPUTE(cur, false, 0, 0)

#undef COMPUTE
#undef BARRIER

  // ---- q/k/v epilogue over the 256x256 tile ----
  constexpr int CS = 264;              // staging row stride (16B-aligned)
  ushort* sm = ring;
  int sec = n0 >> 10;                  // 0=q, 1=k, 2=v (block-uniform)
  int b_ = m0 >> 11, t0 = m0 & 2047;   // 256-row tile never crosses b
  int hb = (n0 & 1023) >> 6;           // head base of this 256-col tile
  __syncthreads();                     // K-loop LDS reads drained

  if (sec < 2) {
    float qs = (sec == 0) ? 0.18033688f : 1.0f;   // 0.125 * log2(e) on q
    ushort* dst = (sec == 0) ? qb : kb;
    int kcol = tid & 7, hrow = tid >> 3;          // hrow 0..63
#pragma unroll 1
    for (int hf = 0; hf < 2; ++hf) {   // m-halves; waves with wm==hf stage
      if (wm == hf) {
#pragma unroll
        for (int mi = 0; mi < 8; mi++)
#pragma unroll
          for (int nj = 0; nj < 4; nj++)
#pragma unroll
            for (int r = 0; r < 4; r++)
              sm[(mi * 16 + quad * 4 + r) * CS + wn64 + nj * 16 + lrow] =
                  f2bf(acc[mi][nj][r] * qs);
      }
      __syncthreads();
#pragma unroll
      for (int ri = 0; ri < 2; ri++)
#pragma unroll
        for (int hh = 0; hh < 4; hh++) {
          int mloc = ri * 64 + hrow;
          uint4 val = *(const uint4*)(&sm[mloc * CS + hh * 64 + kcol * 8]);
          int t = t0 + hf * 128 + mloc;
          *(uint4*)(dst + ((size_t)(b_ * 16 + hb + hh) * 2048 + t) * 64 +
                    kcol * 8) = val;
        }
      __syncthreads();
    }
  } else {
    int kcol = tid & 15, drow = tid >> 4;         // drow 0..31
#pragma unroll 1
    for (int nf = 0; nf < 2; ++nf) {   // n-halves; waves with wn>>1==nf stage
      if ((wn >> 1) == nf) {
        // stage C^T: [n-local][m-local]; frag's 4 values are consecutive m
#pragma unroll
        for (int mi = 0; mi < 8; mi++)
#pragma unroll
          for (int nj = 0; nj < 4; nj++) {
            uint2 w;
            w.x = pack_bf16(acc[mi][nj][0], acc[mi][nj][1]);
            w.y = pack_bf16(acc[mi][nj][2], acc[mi][nj][3]);
            *(uint2*)(&sm[((wn & 1) * 64 + nj * 16 + lrow) * CS + wm128 +
                          mi * 16 + quad * 4]) = w;
          }
      }
      __syncthreads();
#pragma unroll
      for (int di = 0; di < 4; di++)
#pragma unroll
        for (int mi2 = 0; mi2 < 2; mi2++) {
          int nloc = di * 32 + drow;
          int moff = mi2 * 128 + kcol * 8;
          uint4 val = *(const uint4*)(&sm[nloc * CS + moff]);
          int h = hb + nf * 2 + (nloc >> 6), d = nloc & 63;
          *(uint4*)(vt + ((size_t)(b_ * 16 + h) * 64 + d) * 2048 + t0 +
                    moff) = val;
        }
      __syncthreads();
    }
  }
}

// ---------------------------------------------------------------------------
// Output-projection GEMM (round-5 passing kernel, unchanged): C = A @ B^T
// fp32, 128x128 tile, BK=32, 4 waves, ring-3 (48 KiB), raw s_barrier +
// counted vmcnt(4) + 1-tile register pipeline. Grid 64x8 = 512 blocks.
// ---------------------------------------------------------------------------
__global__ __launch_bounds__(256) void gemm_out(const ushort* __restrict__ A,
                                                const ushort* __restrict__ Bw,
                                                float* __restrict__ Cf) {
  constexpr int SLOT = 8192;                  // ushorts per ring slot (A+B)
  __shared__ ushort ring[3 * SLOT];           // 48 KiB
  int tid = threadIdx.x;
  int lane = tid & 63, wave = tid >> 6;
  int lrow = lane & 15, quad = lane >> 4;
  int wr = (wave >> 1) * 64, wc = (wave & 1) * 64;
  int m0 = blockIdx.x * 128, n0 = blockIdx.y * 128;

  int srow = tid >> 2;                                   // 0..63
  int schunk8 = ((tid & 3) ^ ((tid >> 3) & 3)) * 8;
  const ushort* Ag0 = A + (size_t)(m0 + srow) * 1024 + schunk8;
  const ushort* Ag1 = Ag0 + (size_t)64 * 1024;
  const ushort* Bg0 = Bw + (size_t)(n0 + srow) * 1024 + schunk8;
  const ushort* Bg1 = Bg0 + (size_t)64 * 1024;
  int fo2 = (quad ^ ((lrow >> 1) & 3)) * 8;              // frag-read chunk

  const floatx4 zero4 = {0.f, 0.f, 0.f, 0.f};
  floatx4 acc[4][4];
#pragma unroll
  for (int i = 0; i < 4; i++)
#pragma unroll
    for (int j = 0; j < 4; j++) acc[i][j] = zero4;

  auto stage = [&](int t) {
    ushort* Sa = &ring[(t % 3) * SLOT];
    size_t kk = (size_t)t * 32;
    gload16(Ag0 + kk, &Sa[wave * 16 * 32]);              // A rows  0..63
    gload16(Ag1 + kk, &Sa[(64 + wave * 16) * 32]);       // A rows 64..127
    gload16(Bg0 + kk, &Sa[4096 + wave * 16 * 32]);       // B rows  0..63
    gload16(Bg1 + kk, &Sa[4096 + (64 + wave * 16) * 32]);// B rows 64..127
  };

  short8 fAa[4], fAb[4], fBa[4], fBb[4];

#define READF(u_, FN)                                                         \
  {                                                                           \
    ushort* As_ = &ring[((u_) % 3) * SLOT];                                   \
    ushort* Bs_ = As_ + 4096;                                                 \
    _Pragma("unroll")                                                         \
    for (int mi = 0; mi < 4; mi++)                                            \
      FN##a[mi] = *(const short8*)(&As_[(wr + mi * 16 + lrow) * 32 + fo2]);   \
    _Pragma("unroll")                                                         \
    for (int nj = 0; nj < 4; nj++)                                            \
      FN##b[nj] = *(const short8*)(&Bs_[(wc + nj * 16 + lrow) * 32 + fo2]);   \
  }

#define MFMAS(FC)                                                             \
  {                                                                           \
    __builtin_amdgcn_s_setprio(1);                                            \
    _Pragma("unroll")                                                         \
    for (int mi = 0; mi < 4; mi++)                                            \
      _Pragma("unroll")                                                       \
      for (int nj = 0; nj < 4; nj++)                                          \
        acc[mi][nj] = __builtin_amdgcn_mfma_f32_16x16x32_bf16(                \
            FC##a[mi], FC##b[nj], acc[mi][nj], 0, 0, 0);                      \
    __builtin_amdgcn_s_setprio(0);                                            \
  }

#define BARRIER(N_)                                                           \
  asm volatile("s_waitcnt vmcnt(" #N_ ")" ::: "memory");                      \
  __builtin_amdgcn_s_barrier();                                               \
  asm volatile("" ::: "memory");

#define KITER(u_, N_, ISSUE_, FC, FN)                                         \
  {                                                                           \
    BARRIER(N_)                                                               \
    READF(u_, FN)                                                             \
    if (ISSUE_) stage((u_) + 2);                                              \
    MFMAS(FC)                                                                 \
  }

  stage(0); stage(1);
  BARRIER(4)                      // tile 0 landed (4 = tile 1 in flight)
  READF(0, fA)
  stage(2);
#pragma unroll 1
  for (int p = 0; p < 14; ++p) {  // u = 1..28, stages 3..30
    KITER(2 * p + 1, 4, true, fA, fB);
    KITER(2 * p + 2, 4, true, fB, fA);
  }
  KITER(29, 4, true, fA, fB);     // stage(31); outstanding t30,t31
  KITER(30, 4, false, fB, fA);    // retire t30; outstanding t31
  KITER(31, 0, false, fA, fB);    // retire t31
  MFMAS(fB)                       // tile 31 compute

#undef KITER
#undef BARRIER
#undef MFMAS
#undef READF

#pragma unroll
  for (int mi = 0; mi < 4; mi++)
#pragma unroll
    for (int nj = 0; nj < 4; nj++)
#pragma unroll
      for (int r = 0; r < 4; r++) {
        int m = m0 + wr + mi * 16 + quad * 4 + r;
        int n = n0 + wc + nj * 16 + lrow;
        Cf[(size_t)m * 1024 + n] = acc[mi][nj][r];
      }
}

// Flash attention (round-5 passing kernel, unchanged), causal, no-max softmax
// via exp2 (q pre-scaled by 0.125*log2e). k: [B*H,T,64]; v: [B*H,64,T] bf16.
// 128-row q-tile per block, 8 waves; K/V reg-staged with raw-s_barrier T14
// prefetch (no vmcnt drain in loop). Grid 8x64 = 512 uniform blocks.
__global__ __launch_bounds__(512) void attn_kernel(const ushort* __restrict__ qg,
                                                   const ushort* __restrict__ kg,
                                                   const ushort* __restrict__ vg,
                                                   ushort* __restrict__ y) {
  __shared__ ushort Ks[64 * 64];
  __shared__ ushort Vs[64 * 64];
  __shared__ ushort Ps[8 * 16 * 72];       // per-wave P scratch, stride 72
  int tid = threadIdx.x;
  int lane = tid & 63, wave = tid >> 6;
  int lrow = lane & 15, quad = lane >> 4;
  int gx = blockIdx.x, gy = blockIdx.y;
  int pr = gy >> 3;                        // pair index 0..7
  int bh = (gy & 7) * 8 + gx;              // all blocks of one bh share id%8
  const ushort* qp = qg + (size_t)bh * 2048 * 64;
  const ushort* kp = kg + (size_t)bh * 2048 * 64;
  const ushort* vp = vg + (size_t)bh * 64 * 2048;
  int b = bh >> 4, h = bh & 15;
  int srow = tid >> 3, sc = tid & 7;                    // staging row/chunk
  int sswz = ((sc ^ (srow & 7)) * 8);                   // swizzled LDS chunk
  int fo = (quad ^ (lrow & 7)) * 8;                     // frag-read chunk
  ushort* Pw = &Ps[wave * 16 * 72];

  const floatx4 zero4 = {0.f, 0.f, 0.f, 0.f};
  short8 ones;
#pragma unroll
  for (int i = 0; i < 8; i++) ones[i] = (short)0x3F80;  // bf16 1.0

#pragma unroll 1
  for (int pass = 0; pass < 2; ++pass) {
    int qt = pass ? (15 - pr) : pr;        // 128-row q-tile index 0..15
    int last = 2 * qt + 1;                 // kv tiles 0..last (64-wide)

    const ushort* qrow_p = qp + (size_t)((qt << 7) + wave * 16 + lrow) * 64;
    short8 a_q0 = *(const short8*)(qrow_p + quad * 8);
    short8 a_q1 = *(const short8*)(qrow_p + (quad ^ 4) * 8);

    uint4 kreg = *(const uint4*)(kp + (size_t)srow * 64 + sc * 8);
    uint4 vreg = *(const uint4*)(vp + (size_t)srow * 2048 + sc * 8);

    floatx4 l_acc = zero4;
    floatx4 o_acc[4];
#pragma unroll
    for (int j = 0; j < 4; j++) o_acc[j] = zero4;

#pragma unroll 1
    for (int kv = 0; kv <= last; kv++) {
      // barrier1: prev tile's LDS reads were all consumed by MFMAs (lgkm
      // drained per-wave) -> bare rendezvous; prefetch loads stay in flight.
      asm volatile("" ::: "memory");
      __builtin_amdgcn_s_barrier();
      asm volatile("" ::: "memory");
      *(uint4*)(&Ks[srow * 64 + sswz]) = kreg;
      *(uint4*)(&Vs[srow * 64 + sswz]) = vreg;
      if (kv < last) {                     // issue next tile's loads now
        kreg = *(const uint4*)(kp + (size_t)((kv + 1) * 64 + srow) * 64 + sc * 8);
        vreg = *(const uint4*)(vp + (size_t)srow * 2048 + (kv + 1) * 64 + sc * 8);
      }
      // barrier2: ds_writes visible to all waves; do NOT drain vmcnt.
      asm volatile("s_waitcnt lgkmcnt(0)" ::: "memory");
      __builtin_amdgcn_s_barrier();
      asm volatile("" ::: "memory");

      floatx4 s[4];
#pragma unroll
      for (int ct = 0; ct < 4; ct++) {
        short8 k0 = *(const short8*)(&Ks[(ct * 16 + lrow) * 64 + fo]);
        short8 k1 = *(const short8*)(&Ks[(ct * 16 + lrow) * 64 + (fo ^ 32)]);
        floatx4 z = zero4;
        z = __builtin_amdgcn_mfma_f32_16x16x32_bf16(k0, a_q0, z, 0, 0, 0);
        z = __builtin_amdgcn_mfma_f32_16x16x32_bf16(k1, a_q1, z, 0, 0, 0);
        s[ct] = z;   // row = kv_local = ct*16 + quad*4 + r, col = q = lane&15
      }

      if (kv >= 2 * qt) {
        int qabs = (qt << 7) + wave * 16 + lrow;
        int kbase = (kv << 6) + quad * 4;
#pragma unroll
        for (int ct = 0; ct < 4; ct++)
#pragma unroll
          for (int r = 0; r < 4; r++)
            if (kbase + ct * 16 + r > qabs) s[ct][r] = -1e30f;
      }

#pragma unroll
      for (int ct = 0; ct < 4; ct++) {
        float p0 = __ocml_native_exp2_f32(s[ct][0]);
        float p1 = __ocml_native_exp2_f32(s[ct][1]);
        float p2 = __ocml_native_exp2_f32(s[ct][2]);
        float p3 = __ocml_native_exp2_f32(s[ct][3]);
        uint2 w;
        w.x = pack_bf16(p0, p1);
        w.y = pack_bf16(p2, p3);
        *(uint2*)(&Pw[lrow * 72 + ct * 16 + quad * 4]) = w;
      }
      asm volatile("" ::: "memory");

      short8 a_p0 = *(const short8*)(&Pw[lrow * 72 + quad * 8]);
      short8 a_p1 = *(const short8*)(&Pw[lrow * 72 + 32 + quad * 8]);
      l_acc = __builtin_amdgcn_mfma_f32_16x16x32_bf16(a_p0, ones, l_acc, 0, 0, 0);
      l_acc = __builtin_amdgcn_mfma_f32_16x16x32_bf16(a_p1, ones, l_acc, 0, 0, 0);
#pragma unroll
      for (int j = 0; j < 4; j++) {
        short8 v0 = *(const short8*)(&Vs[(j * 16 + lrow) * 64 + fo]);
        short8 v1 = *(const short8*)(&Vs[(j * 16 + lrow) * 64 + (fo ^ 32)]);
        o_acc[j] = __builtin_amdgcn_mfma_f32_16x16x32_bf16(a_p0, v0, o_acc[j], 0, 0, 0);
        o_acc[j] = __builtin_amdgcn_mfma_f32_16x16x32_bf16(a_p1, v1, o_acc[j], 0, 0, 0);
      }
    }

    float inv[4];
#pragma unroll
    for (int r = 0; r < 4; r++) inv[r] = 1.0f / l_acc[r];

#pragma unroll
    for (int j = 0; j < 4; j++)
#pragma unroll
      for (int r = 0; r < 4; r++) {
        int t = (qt << 7) + wave * 16 + quad * 4 + r;
        y[((size_t)b * 2048 + t) * 1024 + h * 64 + j * 16 + lrow] =
            f2bf(o_acc[j][r] * inv[r]);
      }
  }
}

extern "C" void kernel_launch(void* const* d_in, const int* in_sizes, int n_in,
                              void* d_out, int out_size, void* d_ws, size_t ws_size,
                              hipStream_t stream) {
  const float* x     = (const float*)d_in[0];  // [4,2048,1024]
  const float* w_qkv = (const float*)d_in[1];  // [3072,1024]
  const float* wo    = (const float*)d_in[2];  // [1024,1024]
  float* out = (float*)d_out;                  // [4,2048,1024] fp32

  ushort* x_bf    = (ushort*)d_ws;                         // 8192*1024
  ushort* wqkv_bf = x_bf + (size_t)8192 * 1024;            // 3072*1024
  ushort* wo_bf   = wqkv_bf + (size_t)3072 * 1024;         // 1024*1024
  ushort* qb      = wo_bf + (size_t)1024 * 1024;           // 4*16*2048*64
  ushort* kb      = qb + (size_t)8388608;
  ushort* vt      = kb + (size_t)8388608;                  // [B*H, 64, 2048]
  ushort* yb      = x_bf;  // alias: x_bf dead after gemm1 (stream-ordered)

  cvt3_kernel<<<12288, 256, 0, stream>>>(x, w_qkv, wo, x_bf, wqkv_bf, wo_bf);
  gemm256<<<dim3(32, 12), 512, 0, stream>>>(x_bf, wqkv_bf, qb, kb, vt);
  attn_kernel<<<dim3(8, 64), 512, 0, stream>>>(qb, kb, vt, yb);
  gemm_out<<<dim3(64, 8), 256, 0, stream>>>(yb, wo_bf, out);
}

// Round 7
// 216.217 us; speedup vs baseline: 1.0498x; 1.0498x over previous
//
#include <hip/hip_runtime.h>
#include <hip/hip_bf16.h>
#include <stdint.h>

// B=4, T=2048, H=16, DH=64, EMB=1024; M = B*T = 8192; N_qkv = 3072.

typedef __attribute__((ext_vector_type(8))) short short8;
typedef __attribute__((ext_vector_type(4))) float floatx4;

extern "C" __device__ float __ocml_native_exp2_f32(float);  // -> v_exp_f32 (2^x)

__device__ __forceinline__ ushort f2bf(float f) {
  uint32_t u = __float_as_uint(f);
  u += 0x7fff + ((u >> 16) & 1);   // RNE; inputs are NaN-free
  return (ushort)(u >> 16);
}

#if __has_builtin(__builtin_amdgcn_cvt_pk_bf16_f32)
typedef __attribute__((ext_vector_type(2))) __bf16 bf16x2;
__device__ __forceinline__ uint32_t pack_bf16(float a, float b) {
  union { bf16x2 v; uint32_t u; } cv;
  cv.v = __builtin_amdgcn_cvt_pk_bf16_f32(a, b);
  return cv.u;
}
#else
__device__ __forceinline__ uint32_t pack_bf16(float a, float b) {
  uint32_t ua = __float_as_uint(a) + 0x8000u;
  uint32_t ub = __float_as_uint(b) + 0x8000u;
  return __builtin_amdgcn_perm(ub, ua, 0x07060302u);
}
#endif

// async global->LDS, 16B per lane; LDS dest is wave-uniform base + lane*16
__device__ __forceinline__ void gload16(const ushort* g, ushort* l) {
  __builtin_amdgcn_global_load_lds(
      (const __attribute__((address_space(1))) void*)g,
      (__attribute__((address_space(3))) void*)l, 16, 0, 0);
}

// merged fp32->bf16 convert of x (2097152 float4), w_qkv (786432), wo (262144)
__global__ __launch_bounds__(256) void cvt3_kernel(const float* __restrict__ x,
                                                   const float* __restrict__ wq,
                                                   const float* __restrict__ wo,
                                                   ushort* __restrict__ xo,
                                                   ushort* __restrict__ wqo,
                                                   ushort* __restrict__ woo) {
  int i = blockIdx.x * 256 + threadIdx.x;
  const float* in; ushort* out; int idx;
  if (i < 2097152)      { in = x;  out = xo;  idx = i; }
  else if (i < 2883584) { in = wq; out = wqo; idx = i - 2097152; }
  else                  { in = wo; out = woo; idx = i - 2883584; }
  float4 v = ((const float4*)in)[idx];
  ushort4 o;
  o.x = f2bf(v.x); o.y = f2bf(v.y); o.z = f2bf(v.z); o.w = f2bf(v.w);
  ((ushort4*)out)[idx] = o;
}

// ---------------------------------------------------------------------------
// QKV GEMM: C = A @ B^T, A:[8192,1024] bf16, Bw:[3072,1024] bf16.
// Tile 256(M) x 128(N), *4 waves* (256 thr) as 2M x 2N -> wave owns 128x64.
// Why 4 waves: (1) per-wave 128x64 raises FLOP per LDS-elem-read 64 -> 85,
// making the MFMA pipe (not LDS) the long pole (cap ~89% vs 67%); (2) regs =
// 128 AGPR acc + ~85 VGPR ~= 215 <= 256 (__launch_bounds__(256,2)) and LDS
// 72 KiB => TWO independent blocks/CU (2 waves/SIMD from different blocks) -
// barriers stop stalling the whole SIMD. rocprof's VGPR_Count excludes AGPRs;
// prior 8-wave variants were 148-252 regs/thread => hard 1 block/CU lockstep.
// Ring of 3 K-tile slots (A 256x32 + B 128x32 = 12288 ushorts = 24 KiB/slot).
// Schedule (proven r3-r5): RAW s_barrier (never __syncthreads in K-loop) +
// counted vmcnt(6) (= next tile's 6 gloads stay in flight across every
// barrier) + stage(u+2) issued between frag reads and the MFMA burst.
// Slot written by stage(u+2) was last ds_read at iter u-1 (reads issued
// before iter-u's barrier; gload's LDS write lands >= L2 latency later).
// LDS swizzle: LDS[r][c] holds global chunk c^((r>>1)&3) (staging pre-
// swizzles the GLOBAL chunk; frag reads use chunk quad^((lrow>>1)&3)).
// Grid 32x24 = 768 blocks; with 2 blocks/CU the drain is smooth (no tail).
// ---------------------------------------------------------------------------
__global__ __launch_bounds__(256, 2) void gemm256(const ushort* __restrict__ A,
                                                  const ushort* __restrict__ Bw,
                                                  ushort* __restrict__ qb,
                                                  ushort* __restrict__ kb,
                                                  ushort* __restrict__ vt) {
  constexpr int SLOT = 12288;                 // ushorts per ring slot (A+B)
  __shared__ ushort ring[3 * SLOT];           // 72 KiB
  int tid = threadIdx.x;
  int lane = tid & 63, wave = tid >> 6;       // wave 0..3
  int lrow = lane & 15, quad = lane >> 4;
  int wm = wave >> 1, wn = wave & 1;          // 2M x 2N wave grid
  int wm128 = wm * 128, wn64 = wn * 64;
  int m0 = blockIdx.x * 256, n0 = blockIdx.y * 128;

  // staging: thread covers (row = tid>>2 of a 64-row call, chunk = tid&3);
  // global chunk pre-swizzled by ((row>>1)&3) = (tid>>3)&3
  int srow = tid >> 2;                                   // 0..63
  int schunk8 = ((tid & 3) ^ ((tid >> 3) & 3)) * 8;
  const ushort* Ag0 = A + (size_t)(m0 + srow) * 1024 + schunk8;
  const ushort* Bg0 = Bw + (size_t)(n0 + srow) * 1024 + schunk8;
  int fo2 = (quad ^ ((lrow >> 1) & 3)) * 8;              // frag-read chunk

  const floatx4 zero4 = {0.f, 0.f, 0.f, 0.f};
  floatx4 acc[8][4];
#pragma unroll
  for (int i = 0; i < 8; i++)
#pragma unroll
    for (int j = 0; j < 4; j++) acc[i][j] = zero4;

  auto stage = [&](int t) {                   // 6 gloads = 1 K-tile
    ushort* Sa = &ring[(t % 3) * SLOT];
    size_t kk = (size_t)t * 32;
    gload16(Ag0 + kk,                       &Sa[wave * 512]);          // A   0..63
    gload16(Ag0 + kk + (size_t)64 * 1024,   &Sa[2048 + wave * 512]);   // A  64..127
    gload16(Ag0 + kk + (size_t)128 * 1024,  &Sa[4096 + wave * 512]);   // A 128..191
    gload16(Ag0 + kk + (size_t)192 * 1024,  &Sa[6144 + wave * 512]);   // A 192..255
    gload16(Bg0 + kk,                       &Sa[8192 + wave * 512]);   // B   0..63
    gload16(Bg0 + kk + (size_t)64 * 1024,   &Sa[10240 + wave * 512]);  // B  64..127
  };

#define BARRIER(N_)                                                           \
  asm volatile("s_waitcnt vmcnt(" #N_ ")" ::: "memory");                      \
  __builtin_amdgcn_s_barrier();                                               \
  asm volatile("" ::: "memory");

#define COMPUTE(CUR_, DOSTAGE_, T_)                                           \
  {                                                                           \
    ushort* As_ = &ring[(CUR_)*SLOT];                                         \
    ushort* Bs_ = As_ + 8192;                                                 \
    short8 a_[8], b_[4];                                                      \
    _Pragma("unroll")                                                         \
    for (int mi = 0; mi < 8; mi++)                                            \
      a_[mi] = *(const short8*)(&As_[(wm128 + mi * 16 + lrow) * 32 + fo2]);   \
    _Pragma("unroll")                                                         \
    for (int nj = 0; nj < 4; nj++)                                            \
      b_[nj] = *(const short8*)(&Bs_[(wn64 + nj * 16 + lrow) * 32 + fo2]);    \
    if (DOSTAGE_) stage(T_);                                                  \
    __builtin_amdgcn_s_setprio(1);                                            \
    _Pragma("unroll")                                                         \
    for (int mi = 0; mi < 8; mi++)                                            \
      _Pragma("unroll")                                                       \
      for (int nj = 0; nj < 4; nj++)                                          \
        acc[mi][nj] = __builtin_amdgcn_mfma_f32_16x16x32_bf16(                \
            a_[mi], b_[nj], acc[mi][nj], 0, 0, 0);                            \
    __builtin_amdgcn_s_setprio(0);                                            \
  }

  stage(0); stage(1);
  int cur = 0;
#pragma unroll 1
  for (int u = 0; u < 30; ++u) {      // tiles 0..29, stages 2..31
    BARRIER(6)                         // tile u landed; tile u+1 in flight
    COMPUTE(cur, true, u + 2)
    cur = (cur == 2) ? 0 : cur + 1;
  }
  BARRIER(6)                           // tile 30 landed; tile 31 in flight
  COMPUTE(cur, false, 0)
  cur = (cur == 2) ? 0 : cur + 1;
  BARRIER(0)                           // tile 31 landed
  COMPUTE(cur, false, 0)

#undef COMPUTE
#undef BARRIER

  // ---- q/k/v epilogue (single staging pass; 4-wave partition) ----
  ushort* sm = ring;
  int sec = n0 >> 10;                  // 0=q, 1=k, 2=v (block-uniform)
  int b_ = m0 >> 11, t0 = m0 & 2047;   // 256-row tile never crosses batch
  int hb = (n0 & 1023) >> 6;           // first head of this 128-col tile
  __syncthreads();                     // K-loop LDS reads drained

  if (sec < 2) {
    constexpr int CS = 136;            // 256 x 136 = 34816 <= 36864 ushorts
    float qs = (sec == 0) ? 0.18033688f : 1.0f;   // 0.125 * log2(e) on q
    ushort* dst = (sec == 0) ? qb : kb;
#pragma unroll
    for (int mi = 0; mi < 8; mi++)
#pragma unroll
      for (int nj = 0; nj < 4; nj++)
#pragma unroll
        for (int r = 0; r < 4; r++)
          sm[(wm128 + mi * 16 + quad * 4 + r) * CS + wn64 + nj * 16 + lrow] =
              f2bf(acc[mi][nj][r] * qs);
    __syncthreads();
    int mrow = tid >> 3, kcol = tid & 7;          // mrow 0..31
#pragma unroll
    for (int mi = 0; mi < 8; mi++)
#pragma unroll
      for (int hh = 0; hh < 2; hh++) {
        int mloc = mi * 32 + mrow;                // 0..255
        uint4 val = *(const uint4*)(&sm[mloc * CS + hh * 64 + kcol * 8]);
        int t = t0 + mloc, h = hb + hh;
        *(uint4*)(dst + ((size_t)(b_ * 16 + h) * 2048 + t) * 64 + kcol * 8) = val;
      }
  } else {
    constexpr int CS2 = 264;           // 128 x 264 = 33792 <= 36864 ushorts
    // stage C^T: [n-local 0..127][m-local 0..255]; frag's 4 vals = consec m
#pragma unroll
    for (int mi = 0; mi < 8; mi++)
#pragma unroll
      for (int nj = 0; nj < 4; nj++) {
        uint2 w;
        w.x = pack_bf16(acc[mi][nj][0], acc[mi][nj][1]);
        w.y = pack_bf16(acc[mi][nj][2], acc[mi][nj][3]);
        *(uint2*)(&sm[(wn64 + nj * 16 + lrow) * CS2 + wm128 + mi * 16 +
                      quad * 4]) = w;
      }
    __syncthreads();
    int drow = tid >> 4, kcol = tid & 15;         // drow 0..15
#pragma unroll
    for (int di = 0; di < 8; di++)
#pragma unroll
      for (int mi2 = 0; mi2 < 2; mi2++) {
        int nloc = di * 16 + drow;                // 0..127
        int moff = mi2 * 128 + kcol * 8;          // 0..255
        uint4 val = *(const uint4*)(&sm[nloc * CS2 + moff]);
        int h = hb + (nloc >> 6), d = nloc & 63;
        *(uint4*)(vt + ((size_t)(b_ * 16 + h) * 64 + d) * 2048 + t0 + moff) =
            val;
      }
  }
}

// ---------------------------------------------------------------------------
// Output-projection GEMM (round-5 passing kernel, unchanged): C = A @ B^T
// fp32, 128x128 tile, BK=32, 4 waves, ring-3 (48 KiB), raw s_barrier +
// counted vmcnt(4) + 1-tile register pipeline. Grid 64x8 = 512 blocks.
// ---------------------------------------------------------------------------
__global__ __launch_bounds__(256) void gemm_out(const ushort* __restrict__ A,
                                                const ushort* __restrict__ Bw,
                                                float* __restrict__ Cf) {
  constexpr int SLOT = 8192;                  // ushorts per ring slot (A+B)
  __shared__ ushort ring[3 * SLOT];           // 48 KiB
  int tid = threadIdx.x;
  int lane = tid & 63, wave = tid >> 6;
  int lrow = lane & 15, quad = lane >> 4;
  int wr = (wave >> 1) * 64, wc = (wave & 1) * 64;
  int m0 = blockIdx.x * 128, n0 = blockIdx.y * 128;

  int srow = tid >> 2;                                   // 0..63
  int schunk8 = ((tid & 3) ^ ((tid >> 3) & 3)) * 8;
  const ushort* Ag0 = A + (size_t)(m0 + srow) * 1024 + schunk8;
  const ushort* Ag1 = Ag0 + (size_t)64 * 1024;
  const ushort* Bg0 = Bw + (size_t)(n0 + srow) * 1024 + schunk8;
  const ushort* Bg1 = Bg0 + (size_t)64 * 1024;
  int fo2 = (quad ^ ((lrow >> 1) & 3)) * 8;              // frag-read chunk

  const floatx4 zero4 = {0.f, 0.f, 0.f, 0.f};
  floatx4 acc[4][4];
#pragma unroll
  for (int i = 0; i < 4; i++)
#pragma unroll
    for (int j = 0; j < 4; j++) acc[i][j] = zero4;

  auto stage = [&](int t) {
    ushort* Sa = &ring[(t % 3) * SLOT];
    size_t kk = (size_t)t * 32;
    gload16(Ag0 + kk, &Sa[wave * 16 * 32]);              // A rows  0..63
    gload16(Ag1 + kk, &Sa[(64 + wave * 16) * 32]);       // A rows 64..127
    gload16(Bg0 + kk, &Sa[4096 + wave * 16 * 32]);       // B rows  0..63
    gload16(Bg1 + kk, &Sa[4096 + (64 + wave * 16) * 32]);// B rows 64..127
  };

  short8 fAa[4], fAb[4], fBa[4], fBb[4];

#define READF(u_, FN)                                                         \
  {                                                                           \
    ushort* As_ = &ring[((u_) % 3) * SLOT];                                   \
    ushort* Bs_ = As_ + 4096;                                                 \
    _Pragma("unroll")                                                         \
    for (int mi = 0; mi < 4; mi++)                                            \
      FN##a[mi] = *(const short8*)(&As_[(wr + mi * 16 + lrow) * 32 + fo2]);   \
    _Pragma("unroll")                                                         \
    for (int nj = 0; nj < 4; nj++)                                            \
      FN##b[nj] = *(const short8*)(&Bs_[(wc + nj * 16 + lrow) * 32 + fo2]);   \
  }

#define MFMAS(FC)                                                             \
  {                                                                           \
    __builtin_amdgcn_s_setprio(1);                                            \
    _Pragma("unroll")                                                         \
    for (int mi = 0; mi < 4; mi++)                                            \
      _Pragma("unroll")                                                       \
      for (int nj = 0; nj < 4; nj++)                                          \
        acc[mi][nj] = __builtin_amdgcn_mfma_f32_16x16x32_bf16(                \
            FC##a[mi], FC##b[nj], acc[mi][nj], 0, 0, 0);                      \
    __builtin_amdgcn_s_setprio(0);                                            \
  }

#define BARRIER(N_)                                                           \
  asm volatile("s_waitcnt vmcnt(" #N_ ")" ::: "memory");                      \
  __builtin_amdgcn_s_barrier();                                               \
  asm volatile("" ::: "memory");

#define KITER(u_, N_, ISSUE_, FC, FN)                                         \
  {                                                                           \
    BARRIER(N_)                                                               \
    READF(u_, FN)                                                             \
    if (ISSUE_) stage((u_) + 2);                                              \
    MFMAS(FC)                                                                 \
  }

  stage(0); stage(1);
  BARRIER(4)                      // tile 0 landed (4 = tile 1 in flight)
  READF(0, fA)
  stage(2);
#pragma unroll 1
  for (int p = 0; p < 14; ++p) {  // u = 1..28, stages 3..30
    KITER(2 * p + 1, 4, true, fA, fB);
    KITER(2 * p + 2, 4, true, fB, fA);
  }
  KITER(29, 4, true, fA, fB);     // stage(31); outstanding t30,t31
  KITER(30, 4, false, fB, fA);    // retire t30; outstanding t31
  KITER(31, 0, false, fA, fB);    // retire t31
  MFMAS(fB)                       // tile 31 compute

#undef KITER
#undef BARRIER
#undef MFMAS
#undef READF

#pragma unroll
  for (int mi = 0; mi < 4; mi++)
#pragma unroll
    for (int nj = 0; nj < 4; nj++)
#pragma unroll
      for (int r = 0; r < 4; r++) {
        int m = m0 + wr + mi * 16 + quad * 4 + r;
        int n = n0 + wc + nj * 16 + lrow;
        Cf[(size_t)m * 1024 + n] = acc[mi][nj][r];
      }
}

// Flash attention (round-5 passing kernel, unchanged), causal, no-max softmax
// via exp2 (q pre-scaled by 0.125*log2e). k: [B*H,T,64]; v: [B*H,64,T] bf16.
// 128-row q-tile per block, 8 waves; K/V reg-staged with raw-s_barrier T14
// prefetch (no vmcnt drain in loop). Grid 8x64 = 512 uniform blocks.
__global__ __launch_bounds__(512) void attn_kernel(const ushort* __restrict__ qg,
                                                   const ushort* __restrict__ kg,
                                                   const ushort* __restrict__ vg,
                                                   ushort* __restrict__ y) {
  __shared__ ushort Ks[64 * 64];
  __shared__ ushort Vs[64 * 64];
  __shared__ ushort Ps[8 * 16 * 72];       // per-wave P scratch, stride 72
  int tid = threadIdx.x;
  int lane = tid & 63, wave = tid >> 6;
  int lrow = lane & 15, quad = lane >> 4;
  int gx = blockIdx.x, gy = blockIdx.y;
  int pr = gy >> 3;                        // pair index 0..7
  int bh = (gy & 7) * 8 + gx;              // all blocks of one bh share id%8
  const ushort* qp = qg + (size_t)bh * 2048 * 64;
  const ushort* kp = kg + (size_t)bh * 2048 * 64;
  const ushort* vp = vg + (size_t)bh * 64 * 2048;
  int b = bh >> 4, h = bh & 15;
  int srow = tid >> 3, sc = tid & 7;                    // staging row/chunk
  int sswz = ((sc ^ (srow & 7)) * 8);                   // swizzled LDS chunk
  int fo = (quad ^ (lrow & 7)) * 8;                     // frag-read chunk
  ushort* Pw = &Ps[wave * 16 * 72];

  const floatx4 zero4 = {0.f, 0.f, 0.f, 0.f};
  short8 ones;
#pragma unroll
  for (int i = 0; i < 8; i++) ones[i] = (short)0x3F80;  // bf16 1.0

#pragma unroll 1
  for (int pass = 0; pass < 2; ++pass) {
    int qt = pass ? (15 - pr) : pr;        // 128-row q-tile index 0..15
    int last = 2 * qt + 1;                 // kv tiles 0..last (64-wide)

    const ushort* qrow_p = qp + (size_t)((qt << 7) + wave * 16 + lrow) * 64;
    short8 a_q0 = *(const short8*)(qrow_p + quad * 8);
    short8 a_q1 = *(const short8*)(qrow_p + (quad ^ 4) * 8);

    uint4 kreg = *(const uint4*)(kp + (size_t)srow * 64 + sc * 8);
    uint4 vreg = *(const uint4*)(vp + (size_t)srow * 2048 + sc * 8);

    floatx4 l_acc = zero4;
    floatx4 o_acc[4];
#pragma unroll
    for (int j = 0; j < 4; j++) o_acc[j] = zero4;

#pragma unroll 1
    for (int kv = 0; kv <= last; kv++) {
      // barrier1: prev tile's LDS reads were all consumed by MFMAs (lgkm
      // drained per-wave) -> bare rendezvous; prefetch loads stay in flight.
      asm volatile("" ::: "memory");
      __builtin_amdgcn_s_barrier();
      asm volatile("" ::: "memory");
      *(uint4*)(&Ks[srow * 64 + sswz]) = kreg;
      *(uint4*)(&Vs[srow * 64 + sswz]) = vreg;
      if (kv < last) {                     // issue next tile's loads now
        kreg = *(const uint4*)(kp + (size_t)((kv + 1) * 64 + srow) * 64 + sc * 8);
        vreg = *(const uint4*)(vp + (size_t)srow * 2048 + (kv + 1) * 64 + sc * 8);
      }
      // barrier2: ds_writes visible to all waves; do NOT drain vmcnt.
      asm volatile("s_waitcnt lgkmcnt(0)" ::: "memory");
      __builtin_amdgcn_s_barrier();
      asm volatile("" ::: "memory");

      floatx4 s[4];
#pragma unroll
      for (int ct = 0; ct < 4; ct++) {
        short8 k0 = *(const short8*)(&Ks[(ct * 16 + lrow) * 64 + fo]);
        short8 k1 = *(const short8*)(&Ks[(ct * 16 + lrow) * 64 + (fo ^ 32)]);
        floatx4 z = zero4;
        z = __builtin_amdgcn_mfma_f32_16x16x32_bf16(k0, a_q0, z, 0, 0, 0);
        z = __builtin_amdgcn_mfma_f32_16x16x32_bf16(k1, a_q1, z, 0, 0, 0);
        s[ct] = z;   // row = kv_local = ct*16 + quad*4 + r, col = q = lane&15
      }

      if (kv >= 2 * qt) {
        int qabs = (qt << 7) + wave * 16 + lrow;
        int kbase = (kv << 6) + quad * 4;
#pragma unroll
        for (int ct = 0; ct < 4; ct++)
#pragma unroll
          for (int r = 0; r < 4; r++)
            if (kbase + ct * 16 + r > qabs) s[ct][r] = -1e30f;
      }

#pragma unroll
      for (int ct = 0; ct < 4; ct++) {
        float p0 = __ocml_native_exp2_f32(s[ct][0]);
        float p1 = __ocml_native_exp2_f32(s[ct][1]);
        float p2 = __ocml_native_exp2_f32(s[ct][2]);
        float p3 = __ocml_native_exp2_f32(s[ct][3]);
        uint2 w;
        w.x = pack_bf16(p0, p1);
        w.y = pack_bf16(p2, p3);
        *(uint2*)(&Pw[lrow * 72 + ct * 16 + quad * 4]) = w;
      }
      asm volatile("" ::: "memory");

      short8 a_p0 = *(const short8*)(&Pw[lrow * 72 + quad * 8]);
      short8 a_p1 = *(const short8*)(&Pw[lrow * 72 + 32 + quad * 8]);
      l_acc = __builtin_amdgcn_mfma_f32_16x16x32_bf16(a_p0, ones, l_acc, 0, 0, 0);
      l_acc = __builtin_amdgcn_mfma_f32_16x16x32_bf16(a_p1, ones, l_acc, 0, 0, 0);
#pragma unroll
      for (int j = 0; j < 4; j++) {
        short8 v0 = *(const short8*)(&Vs[(j * 16 + lrow) * 64 + fo]);
        short8 v1 = *(const short8*)(&Vs[(j * 16 + lrow) * 64 + (fo ^ 32)]);
        o_acc[j] = __builtin_amdgcn_mfma_f32_16x16x32_bf16(a_p0, v0, o_acc[j], 0, 0, 0);
        o_acc[j] = __builtin_amdgcn_mfma_f32_16x16x32_bf16(a_p1, v1, o_acc[j], 0, 0, 0);
      }
    }

    float inv[4];
#pragma unroll
    for (int r = 0; r < 4; r++) inv[r] = 1.0f / l_acc[r];

#pragma unroll
    for (int j = 0; j < 4; j++)
#pragma unroll
      for (int r = 0; r < 4; r++) {
        int t = (qt << 7) + wave * 16 + quad * 4 + r;
        y[((size_t)b * 2048 + t) * 1024 + h * 64 + j * 16 + lrow] =
            f2bf(o_acc[j][r] * inv[r]);
      }
  }
}

extern "C" void kernel_launch(void* const* d_in, const int* in_sizes, int n_in,
                              void* d_out, int out_size, void* d_ws, size_t ws_size,
                              hipStream_t stream) {
  const float* x     = (const float*)d_in[0];  // [4,2048,1024]
  const float* w_qkv = (const float*)d_in[1];  // [3072,1024]
  const float* wo    = (const float*)d_in[2];  // [1024,1024]
  float* out = (float*)d_out;                  // [4,2048,1024] fp32

  ushort* x_bf    = (ushort*)d_ws;                         // 8192*1024
  ushort* wqkv_bf = x_bf + (size_t)8192 * 1024;            // 3072*1024
  ushort* wo_bf   = wqkv_bf + (size_t)3072 * 1024;         // 1024*1024
  ushort* qb      = wo_bf + (size_t)1024 * 1024;           // 4*16*2048*64
  ushort* kb      = qb + (size_t)8388608;
  ushort* vt      = kb + (size_t)8388608;                  // [B*H, 64, 2048]
  ushort* yb      = x_bf;  // alias: x_bf dead after gemm1 (stream-ordered)

  cvt3_kernel<<<12288, 256, 0, stream>>>(x, w_qkv, wo, x_bf, wqkv_bf, wo_bf);
  gemm256<<<dim3(32, 24), 256, 0, stream>>>(x_bf, wqkv_bf, qb, kb, vt);
  attn_kernel<<<dim3(8, 64), 512, 0, stream>>>(qb, kb, vt, yb);
  gemm_out<<<dim3(64, 8), 256, 0, stream>>>(yb, wo_bf, out);
}